// Round 8
// baseline (1467.423 us; speedup 1.0000x reference)
//
#include <hip/hip_runtime.h>
#include <hip/hip_bf16.h>

// B=1024, L=160, D=300. Outputs (proj_T, HCD) fp32.
// Algebra (validated R1-R7, absmax 0.031):
//   projT = T @ Wproj^T + b                  (fp32 -> d_out)      [gemm mode 0]
//   pCD   = CD @ Wproj^T + b  (bf16 frag-order, col300=1)         [gemm mode 1]
//   ZT    = sigm(T_j . wt + c')  via mean-commute algebra         [gate2_k]
//   Y     = pCD @ Maug^T  (bias via pCD col300=1)                 [gemm mode 2]
//   S = Y @ pCD^T ; s_i = sum_j sigm(S_ij) ZT_j W3_j ; alpha = softmax(s)
//   HCD[i,:] = alpha_i * pCD[i,:]                                 [finale_k]
//
// R8: occupancy-first GEMM. Cross-round evidence: every prior structure sat at
// ~2 TB/s with Occupancy 22% (1 block/CU, lockstep drain). Fix: A NEVER in LDS
// (wave-private fragments -> registers; fp32 converted in-reg), LDS = B dbuf
// only (80 KB), wave-tile 32x80 (acc 40 regs), launch_bounds(512,4) caps 128
// VGPR => 2 blocks/CU (16 waves), inter-block TLP hides the barrier drains.
// bf16 matrices in MFMA-fragment order (proven conflict-free: R6 conflicts=0).

typedef __attribute__((ext_vector_type(8))) short short8;
typedef __attribute__((ext_vector_type(4))) float f32x4;

#define DP 320

__device__ __forceinline__ unsigned short f2bf(float x) {
  unsigned int u = __builtin_bit_cast(unsigned int, x);
  u += 0x7FFFu + ((u >> 16) & 1u);
  return (unsigned short)(u >> 16);
}
__device__ __forceinline__ float bf2f(unsigned short h) {
  unsigned int u = ((unsigned int)h) << 16;
  return __builtin_bit_cast(float, u);
}
__device__ __forceinline__ void gload16(const void* g, void* l) {
  __builtin_amdgcn_global_load_lds(
      (const __attribute__((address_space(1))) unsigned int*)g,
      (__attribute__((address_space(3))) unsigned int*)l, 16, 0, 0);
}
__device__ __forceinline__ float sigm(float x) { return 1.0f / (1.0f + __expf(-x)); }
// B-side fragment address (shorts) for element (col n, feat k): kc-major
__device__ __forceinline__ size_t baddr(int n, int k) {
  return (size_t)(k >> 6) * 20480 + (size_t)(n >> 4) * 1024 + ((k >> 5) & 1) * 512 +
         ((((k >> 3) & 3) << 4) | (n & 15)) * 8 + (k & 7);
}
// A-side fragment address (shorts) for element (row r, feat k): row16-major
__device__ __forceinline__ size_t aaddr(size_t r, int k) {
  return ((r >> 4) * 5 + (k >> 6)) * 1024 + ((k >> 5) & 1) * 512 +
         ((((k >> 3) & 3) << 4) | (r & 15)) * 8 + (k & 7);
}

// ---- prep1: job0 Wb(frag)+Wt; job1 MaugT(frag); job2 Pmat(f32) ---------------
__global__ __launch_bounds__(320)
void prep1_k(const float* __restrict__ W,
             const float* __restrict__ WqCD_w, const float* __restrict__ WqCD_b,
             const float* __restrict__ WkCD_w, const float* __restrict__ WkCD_b,
             const float* __restrict__ WqT_w, const float* __restrict__ WqT_b,
             const float* __restrict__ WkT_w, const float* __restrict__ WkT_b,
             unsigned short* __restrict__ Wb, float* __restrict__ Wt,
             unsigned short* __restrict__ MaugT, float* __restrict__ Pmat,
             float isd) {
  const int x = blockIdx.x, c = threadIdx.x;
  if (x < 320) {
    const int n = x;
    unsigned short v = (n < 300 && c < 300) ? f2bf(W[n * 300 + c]) : (unsigned short)0;
    Wb[baddr(n, c)] = v;
    if (n < 300 && c < 300) Wt[c * 304 + n] = W[n * 300 + c];
  } else if (x < 640) {
    const int n = x - 320;
    float v = 0.f;
    if (n <= 300 && c <= 300) {
      for (int o = 0; o < 300; ++o) {
        float a = (c < 300) ? WqCD_w[o * 300 + c] : WqCD_b[o];
        float b = (n < 300) ? WkCD_w[o * 300 + n] : WkCD_b[o];
        v += a * b;
      }
      v *= isd;
    }
    MaugT[baddr(n, c)] = f2bf(v);
  } else {
    const int n = x - 640;
    float v = 0.f;
    if (n <= 300 && c <= 300) {
      for (int o = 0; o < 300; ++o) {
        float a = (c < 300) ? WkT_w[o * 300 + c] : WkT_b[o];
        float b = (n < 300) ? WqT_w[o * 300 + n] : WqT_b[o];
        v += a * b;
      }
      v *= isd;
    }
    Pmat[n * DP + c] = v;
  }
}

// ---- GEMM: 8 waves (2Mx4N), BM=64, BN=320, BK=64, wave-tile 32x80 ------------
// A direct-to-reg (no LDS); B dbuf LDS 2x40KB.
// mode 0: T  @ Wb -> projT fp32 (+bproj)
// mode 1: CD @ Wb -> pCD bf16 frag (+bproj, col300=1)
// mode 2: pCD @ MaugT -> Y bf16 frag
__global__ __launch_bounds__(512, 4)
void gemm_k(const float* __restrict__ Tf, const float* __restrict__ CDf,
            const unsigned short* __restrict__ Ah,
            const unsigned short* __restrict__ B01,
            const unsigned short* __restrict__ B2,
            const float* __restrict__ bias,
            float* __restrict__ Of, unsigned short* __restrict__ pCDout,
            unsigned short* __restrict__ Yout, int mode_base) {
  __shared__ __align__(16) unsigned short Bs[2][20480];   // 2 x 40 KB
  const int tid = threadIdx.x, wid = tid >> 6, lane = tid & 63;
  const int lr = lane & 15, hi = lane >> 4;
  const int wr = wid >> 2, wc = wid & 3;
  const int mode = mode_base + blockIdx.y;
  const size_t m0 = (size_t)blockIdx.x * 64;
  const unsigned short* __restrict__ Bm = (mode == 2) ? B2 : B01;
  const float* __restrict__ Af = (mode == 0) ? Tf : CDf;

  f32x4 acc[2][5];
#pragma unroll
  for (int i = 0; i < 2; ++i)
#pragma unroll
    for (int j = 0; j < 5; ++j) acc[i][j] = (f32x4){0.f, 0.f, 0.f, 0.f};

  f32x4 ar[2][2][2];     // fp32 in-flight A: [mf][kk][half]
  short8 afc[2][2];      // current bf16 A frags
  short8 afn[2][2];      // mode-2 prefetch

  auto loadA_f32 = [&](int kc) {
#pragma unroll
    for (int mf = 0; mf < 2; ++mf) {
      const size_t row = m0 + wr * 32 + mf * 16 + lr;
#pragma unroll
      for (int kk = 0; kk < 2; ++kk) {
        const int col0 = kc * 64 + kk * 32 + hi * 8;
        const float* p = Af + row * 300 + col0;
        if (col0 + 8 <= 300) {
          ar[mf][kk][0] = *(const f32x4*)p;
          ar[mf][kk][1] = *(const f32x4*)(p + 4);
        } else {
#pragma unroll
          for (int j = 0; j < 4; ++j) {
            ar[mf][kk][0][j] = (col0 + j < 300) ? p[j] : 0.f;
            ar[mf][kk][1][j] = (col0 + 4 + j < 300) ? p[4 + j] : 0.f;
          }
        }
      }
    }
  };
  auto cvtA = [&]() {
#pragma unroll
    for (int mf = 0; mf < 2; ++mf)
#pragma unroll
      for (int kk = 0; kk < 2; ++kk) {
        short8 h;
#pragma unroll
        for (int j = 0; j < 4; ++j) {
          h[j] = (short)f2bf(ar[mf][kk][0][j]);
          h[j + 4] = (short)f2bf(ar[mf][kk][1][j]);
        }
        afc[mf][kk] = h;
      }
  };
  auto loadA_h = [&](short8 (&dst)[2][2], int kc) {
#pragma unroll
    for (int mf = 0; mf < 2; ++mf) {
      const size_t rt = (m0 >> 4) + wr * 2 + mf;
#pragma unroll
      for (int kk = 0; kk < 2; ++kk)
        dst[mf][kk] = *(const short8*)(Ah + (rt * 5 + kc) * 1024 + kk * 512 + lane * 8);
    }
  };
  auto stageB = [&](int buf, int kc) {
#pragma unroll
    for (int it = 0; it < 5; ++it) {
      int idx = it * 512 + tid;
      gload16(Bm + (size_t)kc * 20480 + (size_t)idx * 8, (char*)Bs[buf] + (size_t)idx * 16);
    }
  };

  if (mode < 2) { loadA_f32(0); stageB(0, 0); cvtA(); }
  else { loadA_h(afc, 0); stageB(0, 0); }
  __syncthreads();

  for (int kc = 0; kc < 5; ++kc) {
    const int cur = kc & 1;
    if (kc < 4) {
      if (mode < 2) loadA_f32(kc + 1);     // issue A first (older in vmcnt queue)
      else loadA_h(afn, kc + 1);
      stageB(cur ^ 1, kc + 1);
    }
#pragma unroll
    for (int kk = 0; kk < 2; ++kk) {
      short8 b[5];
#pragma unroll
      for (int nf = 0; nf < 5; ++nf)
        b[nf] = *(const short8*)&Bs[cur][(size_t)(wc * 5 + nf) * 1024 + kk * 512 + lane * 8];
#pragma unroll
      for (int mf = 0; mf < 2; ++mf)
#pragma unroll
        for (int nf = 0; nf < 5; ++nf)
          acc[mf][nf] = __builtin_amdgcn_mfma_f32_16x16x32_bf16(afc[mf][kk], b[nf], acc[mf][nf], 0, 0, 0);
    }
    if (kc < 4) {
      if (mode < 2) cvtA();                // waitcnt lands here, after MFMA phase
      else {
#pragma unroll
        for (int mf = 0; mf < 2; ++mf)
#pragma unroll
          for (int kk = 0; kk < 2; ++kk) afc[mf][kk] = afn[mf][kk];
      }
    }
    __syncthreads();
  }

#pragma unroll
  for (int mf = 0; mf < 2; ++mf) {
    const size_t rowb = m0 + wr * 32 + mf * 16 + hi * 4;
#pragma unroll
    for (int nf = 0; nf < 5; ++nf) {
      const int col = wc * 80 + nf * 16 + lr;
      const float bv = (mode < 2) ? ((col < 300) ? bias[col] : 0.f) : 0.f;
#pragma unroll
      for (int r = 0; r < 4; ++r) {
        const size_t rw = rowb + r;
        float v = acc[mf][nf][r] + bv;
        if (mode == 0) {
          if (col < 300) Of[rw * 300 + col] = v;
        } else if (mode == 1) {
          unsigned short u = (col < 300) ? f2bf(v)
                           : ((col == 300) ? f2bf(1.0f) : (unsigned short)0);
          pCDout[aaddr(rw, col)] = u;
        } else {
          Yout[aaddr(rw, col)] = f2bf(v);
        }
      }
    }
  }
}

// ---- gate2: mean(T) -> maug -> vv -> wt -> ZT, from RAW fp32 T ---------------
__global__ __launch_bounds__(320)
void gate2_k(const float* __restrict__ T, const float* __restrict__ Pmat,
             const float* __restrict__ W, const float* __restrict__ Wt,
             const float* __restrict__ bproj, float* __restrict__ ZT) {
  __shared__ float mt[304];
  __shared__ float maug[304];
  __shared__ float vv[304];
  __shared__ float wt[304];
  __shared__ float cpr;
  const int b = blockIdx.x, t = threadIdx.x;
  const int wid = t >> 6, lane = t & 63;
  const float* Tb = T + (size_t)b * 48000;
  if (t < 300) {
    float s = 0.f;
#pragma unroll 4
    for (int l = 0; l < 160; ++l) s += Tb[l * 300 + t];
    mt[t] = s * (1.0f / 160.0f);
  }
  __syncthreads();
  if (t < 304) {
    if (t < 300) {
      float s = 0.f;
      for (int o = 0; o < 300; ++o) s += Wt[o * 304 + t] * mt[o];
      maug[t] = s + bproj[t];
    } else maug[t] = (t == 300) ? 1.f : 0.f;
  }
  __syncthreads();
  if (t < 304) {
    float s = 0.f;
    if (t <= 300) for (int a = 0; a <= 300; ++a) s += Pmat[a * DP + t] * maug[a];
    vv[t] = s;
  }
  __syncthreads();
  if (t < 304) {
    if (t < 300) {
      float s = 0.f;
      for (int c = 0; c < 300; ++c) s += vv[c] * W[c * 300 + t];
      wt[t] = s;
    } else {
      wt[t] = 0.f;
      if (t == 300) {
        float s = 0.f;
        for (int c = 0; c < 300; ++c) s += vv[c] * bproj[c];
        cpr = s + vv[300];
      }
    }
  }
  __syncthreads();
  for (int j = wid * 32; j < wid * 32 + 32; ++j) {
    const float* row = Tb + j * 300;
    float s = 0.f;
    for (int c = lane; c < 300; c += 64) s += wt[c] * row[c];
#pragma unroll
    for (int m = 1; m < 64; m <<= 1) s += __shfl_xor(s, m, 64);
    if (lane == 0) ZT[b * 160 + j] = sigm(s + cpr);
  }
}

// ---- finale: S = Y @ pCD^T, reduce, softmax, HCD -----------------------------
__global__ __launch_bounds__(640)
void finale_k(const unsigned short* __restrict__ Yg, const unsigned short* __restrict__ Pg,
              const float* __restrict__ ZT, const float* __restrict__ W3w,
              float* __restrict__ out) {
  __shared__ __align__(16) unsigned short Ps[51200];   // 100 KB
  __shared__ float t_arr[160];
  __shared__ float s_arr[160];
  __shared__ float red0;
  const int b = blockIdx.x, tid = threadIdx.x, wid = tid >> 6, lane = tid & 63;
  const int lr = lane & 15, hi = lane >> 4;
  const unsigned short* Pb = Pg + (size_t)b * 51200;
  const unsigned short* Yb = Yg + (size_t)b * 51200;

  if (tid < 160) t_arr[tid] = ZT[b * 160 + tid] * W3w[tid];

  auto stageP = [&](int kc) {
#pragma unroll
    for (int it = 0; it < 2; ++it) {
      int idx = it * 640 + tid;
      int r16 = idx >> 7, rem = idx & 127;
      gload16(Pb + ((size_t)r16 * 5 + kc) * 1024 + (size_t)rem * 8,
              (char*)Ps + ((size_t)kc * 10240 + (size_t)idx * 8) * 2);
    }
  };
  short8 yf[2][2];
  auto loadY = [&](short8 (&dst)[2], int kc) {
#pragma unroll
    for (int kk = 0; kk < 2; ++kk)
      dst[kk] = *(const short8*)(Yb + ((size_t)wid * 5 + kc) * 1024 + kk * 512 + lane * 8);
  };

  f32x4 acc[10];
#pragma unroll
  for (int j = 0; j < 10; ++j) acc[j] = (f32x4){0.f, 0.f, 0.f, 0.f};

  stageP(0);
  loadY(yf[0], 0);
  __syncthreads();
#pragma unroll
  for (int kc = 0; kc < 5; ++kc) {
    const int cur = kc & 1;
    if (kc < 4) { stageP(kc + 1); loadY(yf[cur ^ 1], kc + 1); }
#pragma unroll
    for (int kk = 0; kk < 2; ++kk)
#pragma unroll
      for (int nf = 0; nf < 10; ++nf) {
        short8 bb = *(const short8*)&Ps[kc * 10240 + nf * 1024 + kk * 512 + lane * 8];
        acc[nf] = __builtin_amdgcn_mfma_f32_16x16x32_bf16(yf[cur][kk], bb, acc[nf], 0, 0, 0);
      }
    __syncthreads();
  }

  float pp[4];
#pragma unroll
  for (int r = 0; r < 4; ++r) {
    float s = 0.f;
#pragma unroll
    for (int nf = 0; nf < 10; ++nf) s += sigm(acc[nf][r]) * t_arr[nf * 16 + lr];
    pp[r] = s;
  }
#pragma unroll
  for (int m = 1; m < 16; m <<= 1)
#pragma unroll
    for (int r = 0; r < 4; ++r) pp[r] += __shfl_xor(pp[r], m, 64);
  if (lr == 0) {
#pragma unroll
    for (int r = 0; r < 4; ++r) s_arr[wid * 16 + hi * 4 + r] = pp[r];
  }
  __syncthreads();
  if (wid == 0) {
    float v0 = s_arr[lane], v1 = s_arr[lane + 64];
    float v2 = (lane < 32) ? s_arr[lane + 128] : -3.0e38f;
    float mx = fmaxf(fmaxf(v0, v1), v2);
#pragma unroll
    for (int m = 1; m < 64; m <<= 1) mx = fmaxf(mx, __shfl_xor(mx, m, 64));
    float e0 = __expf(v0 - mx), e1 = __expf(v1 - mx);
    float e2 = (lane < 32) ? __expf(v2 - mx) : 0.f;
    s_arr[lane] = e0; s_arr[lane + 64] = e1;
    if (lane < 32) s_arr[lane + 128] = e2;
    float sm = e0 + e1 + e2;
#pragma unroll
    for (int m = 1; m < 64; m <<= 1) sm += __shfl_xor(sm, m, 64);
    if (lane == 0) red0 = 1.0f / sm;
  }
  __syncthreads();
  const float inv = red0;
  float* ob = out + (size_t)b * 48000;
#pragma unroll
  for (int it = 0; it < 10; ++it) {
    int idx = it * 640 + tid;
    int i = idx / 40, g = idx - i * 40;
    int c0 = g * 8;
    if (c0 < 300) {
      short8 pv = *(const short8*)&Ps[(g >> 3) * 10240 + (i >> 4) * 1024 +
                                      ((g >> 2) & 1) * 512 + ((((g & 3) << 4) | (i & 15)) * 8)];
      float sc = s_arr[i] * inv;
      if (c0 + 8 <= 300) {
        f32x4 o0, o1;
#pragma unroll
        for (int j = 0; j < 4; ++j) { o0[j] = sc * bf2f((unsigned short)pv[j]); o1[j] = sc * bf2f((unsigned short)pv[j + 4]); }
        *(f32x4*)(ob + (size_t)i * 300 + c0) = o0;
        *(f32x4*)(ob + (size_t)i * 300 + c0 + 4) = o1;
      } else {
#pragma unroll
        for (int j = 0; j < 8; ++j) {
          int c = c0 + j;
          if (c < 300) ob[(size_t)i * 300 + c] = sc * bf2f((unsigned short)pv[j]);
        }
      }
    }
  }
}

extern "C" void kernel_launch(void* const* d_in, const int* in_sizes, int n_in,
                              void* d_out, int out_size, void* d_ws, size_t ws_size,
                              hipStream_t stream) {
  (void)in_sizes; (void)n_in; (void)out_size; (void)ws_size;
  const float* T      = (const float*)d_in[0];
  const float* CD     = (const float*)d_in[1];
  const float* Wproj  = (const float*)d_in[2];
  const float* bproj  = (const float*)d_in[3];
  const float* WqT_w  = (const float*)d_in[4];
  const float* WqT_b  = (const float*)d_in[5];
  const float* WqCD_w = (const float*)d_in[6];
  const float* WqCD_b = (const float*)d_in[7];
  const float* WkT_w  = (const float*)d_in[8];
  const float* WkT_b  = (const float*)d_in[9];
  const float* WkCD_w = (const float*)d_in[10];
  const float* WkCD_b = (const float*)d_in[11];
  const float* W3_w   = (const float*)d_in[12];
  // W3_b unused: softmax is shift-invariant.

  char* ws = (char*)d_ws;
  size_t off = 0;
  auto alloc = [&](size_t bytes) { void* p = ws + off; off = (off + bytes + 255) & ~(size_t)255; return p; };
  unsigned short* Wb    = (unsigned short*)alloc((size_t)DP * DP * 2);
  unsigned short* MaugT = (unsigned short*)alloc((size_t)DP * DP * 2);
  float* Pmat = (float*)alloc((size_t)DP * DP * 4);
  float* Wt   = (float*)alloc((size_t)304 * 304 * 4);
  float* ZT   = (float*)alloc((size_t)1024 * 160 * 4);
  unsigned short* pCDg = (unsigned short*)alloc((size_t)163840 * DP * 2);  // 100 MB
  unsigned short* Yg   = (unsigned short*)alloc((size_t)163840 * DP * 2);  // 100 MB

  float* projT = (float*)d_out;
  float* HCD   = (float*)d_out + (size_t)49152000;

  const float isd = 1.0f / sqrtf(300.0f);

  prep1_k<<<dim3(960), dim3(320), 0, stream>>>(Wproj, WqCD_w, WqCD_b, WkCD_w, WkCD_b,
                                               WqT_w, WqT_b, WkT_w, WkT_b,
                                               Wb, Wt, MaugT, Pmat, isd);
  // modes 0,1: projT + pCD from fp32 inputs (in-register bf16 convert, no A-LDS)
  gemm_k<<<dim3(2560, 2), dim3(512), 0, stream>>>(T, CD, nullptr, Wb, nullptr,
                                                  bproj, projT, pCDg, nullptr, 0);
  // mode 2: Y = pCD @ Maug^T
  gemm_k<<<dim3(2560, 1), dim3(512), 0, stream>>>(nullptr, nullptr, pCDg, nullptr, MaugT,
                                                  nullptr, nullptr, nullptr, Yg, 2);
  gate2_k<<<dim3(1024), dim3(320), 0, stream>>>(T, Pmat, Wproj, Wt, bproj, ZT);
  finale_k<<<dim3(1024), dim3(640), 0, stream>>>(Yg, pCDg, ZT, W3_w, HCD);
}

// Round 10
// 673.683 us; speedup vs baseline: 2.1782x; 2.1782x over previous
//
#include <hip/hip_runtime.h>
#include <hip/hip_bf16.h>

// B=1024, L=160, D=300. Outputs (proj_T, HCD) fp32.
// R9b: FULL PER-BATCH FUSION (R9 + typedef fix: short4 -> s16x4; HIP defines
// its own short4). One block per batch. Validated algebra (R1-R8):
//   projT = T@W^T+b (write-only); meanT = mean(projT); vT = Pmat^T[maug;1];
//   ZT = sigm(projT.vT + cT); pCD = CD@W^T+b (col300=1, bf16 frags in LDS);
//   Y = pCD@Maug^T (slab-wise, never materialized); S = Y@pCD^T;
//   s_i = sum_j sigm(S_ij) ZT_j W3_j; alpha = softmax(s); HCD = alpha*pCD.
// HBM traffic = essential only (~800 MB). Weights stream from L2.
// Frag layouts identical to R6-R8 (validated): A-side row16-major, B-side
// kc-major; lane-contiguous ds_read_b128, conflict-free.

typedef __attribute__((ext_vector_type(8))) short short8;
typedef __attribute__((ext_vector_type(4))) short s16x4;
typedef __attribute__((ext_vector_type(4))) float f32x4;

#define DP 320

__device__ __forceinline__ unsigned short f2bf(float x) {
  unsigned int u = __builtin_bit_cast(unsigned int, x);
  u += 0x7FFFu + ((u >> 16) & 1u);
  return (unsigned short)(u >> 16);
}
__device__ __forceinline__ float bf2f(unsigned short h) {
  unsigned int u = ((unsigned int)h) << 16;
  return __builtin_bit_cast(float, u);
}
__device__ __forceinline__ void gload16(const void* g, void* l) {
  __builtin_amdgcn_global_load_lds(
      (const __attribute__((address_space(1))) unsigned int*)g,
      (__attribute__((address_space(3))) unsigned int*)l, 16, 0, 0);
}
__device__ __forceinline__ float sigm(float x) { return 1.0f / (1.0f + __expf(-x)); }
// B-side fragment address (shorts), kc-major (validated R6-R8)
__device__ __forceinline__ size_t baddr(int n, int k) {
  return (size_t)(k >> 6) * 20480 + (size_t)(n >> 4) * 1024 + ((k >> 5) & 1) * 512 +
         ((((k >> 3) & 3) << 4) | (n & 15)) * 8 + (k & 7);
}
// local A-side fragment address (shorts) for 160-row LDS tile
__device__ __forceinline__ int laddr(int row, int k) {
  return ((row >> 4) * 5 + (k >> 6)) * 1024 + ((k >> 5) & 1) * 512 +
         ((((k >> 3) & 3) << 4) | (row & 15)) * 8 + (k & 7);
}

// ---- prep1: job0 Wb(frag); job1 MaugT(frag); job2 Pmat(f32) ------------------
__global__ __launch_bounds__(320)
void prep1_k(const float* __restrict__ W,
             const float* __restrict__ WqCD_w, const float* __restrict__ WqCD_b,
             const float* __restrict__ WkCD_w, const float* __restrict__ WkCD_b,
             const float* __restrict__ WqT_w, const float* __restrict__ WqT_b,
             const float* __restrict__ WkT_w, const float* __restrict__ WkT_b,
             unsigned short* __restrict__ Wb, unsigned short* __restrict__ MaugT,
             float* __restrict__ Pmat, float isd) {
  const int x = blockIdx.x, c = threadIdx.x;
  if (x < 320) {
    const int n = x;
    unsigned short v = (n < 300 && c < 300) ? f2bf(W[n * 300 + c]) : (unsigned short)0;
    Wb[baddr(n, c)] = v;
  } else if (x < 640) {
    const int n = x - 320;
    float v = 0.f;
    if (n <= 300 && c <= 300) {
      for (int o = 0; o < 300; ++o) {
        float a = (c < 300) ? WqCD_w[o * 300 + c] : WqCD_b[o];
        float b = (n < 300) ? WkCD_w[o * 300 + n] : WkCD_b[o];
        v += a * b;
      }
      v *= isd;
    }
    MaugT[baddr(n, c)] = f2bf(v);
  } else {
    const int n = x - 640;
    float v = 0.f;
    if (n <= 300 && c <= 300) {
      for (int o = 0; o < 300; ++o) {
        float a = (c < 300) ? WkT_w[o * 300 + c] : WkT_b[o];
        float b = (n < 300) ? WqT_w[o * 300 + n] : WqT_b[o];
        v += a * b;
      }
      v *= isd;
    }
    Pmat[n * DP + c] = v;
  }
}

// ---- fused per-batch kernel: 640 threads (10 waves, 5M x 2N) -----------------
__global__ __launch_bounds__(640, 2)
void fused_k(const float* __restrict__ T, const float* __restrict__ CD,
             const float* __restrict__ bproj,
             const unsigned short* __restrict__ Wb,
             const unsigned short* __restrict__ MaugT,
             const float* __restrict__ Pmat, const float* __restrict__ W3w,
             float* __restrict__ projT, float* __restrict__ HCD) {
  __shared__ __align__(16) unsigned short Xbf[51200];    // 100 KB: T_bf -> CD_bf -> pCD
  __shared__ __align__(16) unsigned short Wl[2][10240];  // 40 KB: W slabs; later Ys alias
  __shared__ float meanT[304];
  __shared__ float vT[320];
  __shared__ float t_arr[160];
  __shared__ float s_part[2][160];
  __shared__ float s_arr[160];
  __shared__ float red0;

  const int b = blockIdx.x, tid = threadIdx.x;
  const int wid = tid >> 6, lane = tid & 63, lr = lane & 15, hi = lane >> 4;
  const int wm = wid >> 1, wn = wid & 1;

  if (tid < 304) meanT[tid] = 0.f;

  // ---- stage src (fp32, 160x300) -> Xbf frags (bf16, padded K=320) ----
  auto stageX = [&](const float* src) {
#pragma unroll
    for (int cc = 0; cc < 19; ++cc) {
      int idx = cc * 2560 + tid * 4;
      if (idx < 48000) {
        f32x4 v = *(const f32x4*)(src + idx);
        int row = idx / 300;
        int col = idx - row * 300;
        s16x4 p;
#pragma unroll
        for (int j = 0; j < 4; ++j) p[j] = (short)f2bf(v[j]);
        *(s16x4*)&Xbf[laddr(row, col)] = p;
      }
    }
    for (int z = tid; z < 3200; z += 640) {   // zero-pad cols 300..319
      int row = z / 20, col = 300 + (z - (z / 20) * 20);
      Xbf[laddr(row, col)] = 0;
    }
  };
  // ---- stage one BK=32 slab of Wb into Wl[buf] ----
  auto stageW = [&](int buf, int kcc) {
#pragma unroll
    for (int it = 0; it < 2; ++it) {
      int idx = it * 640 + tid;   // 1280 x 16B = 20 KB
      gload16(Wb + (size_t)(kcc >> 1) * 20480 + (size_t)(idx >> 6) * 1024 +
                  (kcc & 1) * 512 + (idx & 63) * 8,
              (char*)Wl[buf] + (size_t)idx * 16);
    }
  };

  f32x4 acc[2][10];
  auto zeroacc = [&]() {
#pragma unroll
    for (int i = 0; i < 2; ++i)
#pragma unroll
      for (int j = 0; j < 10; ++j) acc[i][j] = (f32x4){0.f, 0.f, 0.f, 0.f};
  };
  // ---- X(LDS frags) @ Wb(slabs) -> acc[mf][nf], wave tile 32x160 ----
  auto gemmW = [&]() {
    zeroacc();
    stageW(0, 0);
    __syncthreads();
    for (int kcc = 0; kcc < 10; ++kcc) {
      const int cur = kcc & 1;
      if (kcc < 9) stageW(cur ^ 1, kcc + 1);
      short8 a[2], bb[10];
#pragma unroll
      for (int mf = 0; mf < 2; ++mf)
        a[mf] = *(const short8*)&Xbf[((wm * 2 + mf) * 5 + (kcc >> 1)) * 1024 +
                                     (kcc & 1) * 512 + lane * 8];
#pragma unroll
      for (int nf = 0; nf < 10; ++nf)
        bb[nf] = *(const short8*)&Wl[cur][(wn * 10 + nf) * 512 + lane * 8];
#pragma unroll
      for (int mf = 0; mf < 2; ++mf)
#pragma unroll
        for (int nf = 0; nf < 10; ++nf)
          acc[mf][nf] = __builtin_amdgcn_mfma_f32_16x16x32_bf16(a[mf], bb[nf], acc[mf][nf], 0, 0, 0);
      __syncthreads();
    }
  };

  // ================= Phase A: projT + gate =================
  stageX(T + (size_t)b * 48000);
  __syncthreads();
  gemmW();

  float bv[10];
#pragma unroll
  for (int nf = 0; nf < 10; ++nf) {
    int col = wn * 160 + nf * 16 + lr;
    bv[nf] = (col < 300) ? bproj[col] : 0.f;
  }
  // write projT (fp32, essential traffic)
#pragma unroll
  for (int mf = 0; mf < 2; ++mf)
#pragma unroll
    for (int nf = 0; nf < 10; ++nf) {
      int col = wn * 160 + nf * 16 + lr;
      if (col < 300) {
#pragma unroll
        for (int r = 0; r < 4; ++r) {
          size_t row = (size_t)b * 160 + wm * 32 + mf * 16 + hi * 4 + r;
          projT[row * 300 + col] = acc[mf][nf][r] + bv[nf];
        }
      }
    }
  // meanT: per-lane col sums (bias added later), reduce over hi, atomic over waves
  {
    float cs[10];
#pragma unroll
    for (int nf = 0; nf < 10; ++nf) {
      float s = 0.f;
#pragma unroll
      for (int mf = 0; mf < 2; ++mf)
#pragma unroll
        for (int r = 0; r < 4; ++r) s += acc[mf][nf][r];
      s += __shfl_xor(s, 16, 64);
      s += __shfl_xor(s, 32, 64);
      cs[nf] = s;
    }
    if (hi == 0) {
#pragma unroll
      for (int nf = 0; nf < 10; ++nf) {
        int col = wn * 160 + nf * 16 + lr;
        if (col < 300) atomicAdd(&meanT[col], cs[nf]);
      }
    }
  }
  __syncthreads();
  if (tid < 300) meanT[tid] = meanT[tid] * (1.0f / 160.0f) + bproj[tid];
  __syncthreads();
  // vT[c] = sum_a Pmat[a][c]*maug[a] + Pmat[300][c];  vT[300] = cT
  if (tid < 320) {
    float s = 0.f;
    if (tid <= 300) {
      for (int a2 = 0; a2 < 300; ++a2) s += Pmat[a2 * DP + tid] * meanT[a2];
      s += Pmat[300 * DP + tid];
    }
    vT[tid] = s;
  }
  __syncthreads();
  // ZT: per-row dot(projT_row, vT) from acc regs (acc cols>=300 are 0)
  {
    float zp[2][4];
#pragma unroll
    for (int mf = 0; mf < 2; ++mf)
#pragma unroll
      for (int r = 0; r < 4; ++r) {
        float s = 0.f;
#pragma unroll
        for (int nf = 0; nf < 10; ++nf) {
          int col = wn * 160 + nf * 16 + lr;
          s += (acc[mf][nf][r] + ((col < 300) ? bv[nf] : 0.f)) * vT[col];
        }
        zp[mf][r] = s;
      }
#pragma unroll
    for (int m = 1; m < 16; m <<= 1)
#pragma unroll
      for (int mf = 0; mf < 2; ++mf)
#pragma unroll
        for (int r = 0; r < 4; ++r) zp[mf][r] += __shfl_xor(zp[mf][r], m, 64);
    if (lr == 0) {
#pragma unroll
      for (int mf = 0; mf < 2; ++mf)
#pragma unroll
        for (int r = 0; r < 4; ++r)
          s_part[wn][wm * 32 + mf * 16 + hi * 4 + r] = zp[mf][r];
    }
  }
  __syncthreads();
  if (tid < 160)
    t_arr[tid] = sigm(s_part[0][tid] + s_part[1][tid] + vT[300]) * W3w[tid];
  __syncthreads();

  // ================= Phase B: pCD =================
  stageX(CD + (size_t)b * 48000);
  __syncthreads();
  gemmW();
  // store pCD frags into Xbf (overwrite CD_bf; wave-private rows, post-barrier)
#pragma unroll
  for (int mf = 0; mf < 2; ++mf)
#pragma unroll
    for (int nf = 0; nf < 10; ++nf) {
      int col = wn * 160 + nf * 16 + lr;
#pragma unroll
      for (int r = 0; r < 4; ++r) {
        int row = wm * 32 + mf * 16 + hi * 4 + r;
        unsigned short u = (col < 300) ? f2bf(acc[mf][nf][r] + bv[nf])
                         : ((col == 300) ? (unsigned short)0x3F80 : (unsigned short)0);
        Xbf[laddr(row, col)] = u;
      }
    }
  __syncthreads();

  // ================= Phase C/D: Y slabs + S accumulate =================
  unsigned short* Ys = Wl[0];   // 20 KB alias (W slabs dead)
  f32x4 accs[2][5];
#pragma unroll
  for (int i = 0; i < 2; ++i)
#pragma unroll
    for (int j = 0; j < 5; ++j) accs[i][j] = (f32x4){0.f, 0.f, 0.f, 0.f};

  for (int slab = 0; slab < 5; ++slab) {
    f32x4 ay[2][2];
#pragma unroll
    for (int i = 0; i < 2; ++i)
#pragma unroll
      for (int j = 0; j < 2; ++j) ay[i][j] = (f32x4){0.f, 0.f, 0.f, 0.f};
    // Yslab = pCD(LDS) @ Maug^T[slab cols]  (B-frags direct from L2)
#pragma unroll
    for (int kcc = 0; kcc < 10; ++kcc) {
      short8 a[2], bb2[2];
#pragma unroll
      for (int mf = 0; mf < 2; ++mf)
        a[mf] = *(const short8*)&Xbf[((wm * 2 + mf) * 5 + (kcc >> 1)) * 1024 +
                                     (kcc & 1) * 512 + lane * 8];
#pragma unroll
      for (int nf = 0; nf < 2; ++nf)
        bb2[nf] = *(const short8*)(MaugT + (size_t)(kcc >> 1) * 20480 +
                                   (size_t)(slab * 4 + wn * 2 + nf) * 1024 +
                                   (kcc & 1) * 512 + lane * 8);
#pragma unroll
      for (int mf = 0; mf < 2; ++mf)
#pragma unroll
        for (int nf = 0; nf < 2; ++nf)
          ay[mf][nf] = __builtin_amdgcn_mfma_f32_16x16x32_bf16(a[mf], bb2[nf], ay[mf][nf], 0, 0, 0);
    }
    __syncthreads();   // prev slab's Ys reads complete
#pragma unroll
    for (int mf = 0; mf < 2; ++mf)
#pragma unroll
      for (int nf = 0; nf < 2; ++nf)
#pragma unroll
        for (int r = 0; r < 4; ++r) {
          int row = wm * 32 + mf * 16 + hi * 4 + r;
          int c = wn * 32 + nf * 16 + lr;
          Ys[(row >> 4) * 1024 + ((c >> 5) & 1) * 512 +
             ((((c >> 3) & 3) << 4) | (row & 15)) * 8 + (c & 7)] = f2bf(ay[mf][nf][r]);
        }
    __syncthreads();
    // S += Yslab @ pCD[slab K-cols]^T
#pragma unroll
    for (int kk = 0; kk < 2; ++kk) {
      short8 a2[2], b2[5];
#pragma unroll
      for (int mf = 0; mf < 2; ++mf)
        a2[mf] = *(const short8*)&Ys[(wm * 2 + mf) * 1024 + kk * 512 + lane * 8];
#pragma unroll
      for (int nf = 0; nf < 5; ++nf)
        b2[nf] = *(const short8*)&Xbf[((wn * 5 + nf) * 5 + slab) * 1024 + kk * 512 + lane * 8];
#pragma unroll
      for (int mf = 0; mf < 2; ++mf)
#pragma unroll
        for (int nf = 0; nf < 5; ++nf)
          accs[mf][nf] = __builtin_amdgcn_mfma_f32_16x16x32_bf16(a2[mf], b2[nf], accs[mf][nf], 0, 0, 0);
    }
  }

  // ---- row-reduce sigm(S)*t, softmax, HCD ----
  {
    float pp[2][4];
#pragma unroll
    for (int mf = 0; mf < 2; ++mf)
#pragma unroll
      for (int r = 0; r < 4; ++r) {
        float s = 0.f;
#pragma unroll
        for (int nf = 0; nf < 5; ++nf)
          s += sigm(accs[mf][nf][r]) * t_arr[wn * 80 + nf * 16 + lr];
        pp[mf][r] = s;
      }
#pragma unroll
    for (int m = 1; m < 16; m <<= 1)
#pragma unroll
      for (int mf = 0; mf < 2; ++mf)
#pragma unroll
        for (int r = 0; r < 4; ++r) pp[mf][r] += __shfl_xor(pp[mf][r], m, 64);
    if (lr == 0) {
#pragma unroll
      for (int mf = 0; mf < 2; ++mf)
#pragma unroll
        for (int r = 0; r < 4; ++r)
          s_part[wn][wm * 32 + mf * 16 + hi * 4 + r] = pp[mf][r];
    }
  }
  __syncthreads();
  if (tid < 160) s_arr[tid] = s_part[0][tid] + s_part[1][tid];
  __syncthreads();
  if (wid == 0) {
    float v0 = s_arr[lane], v1 = s_arr[lane + 64];
    float v2 = (lane < 32) ? s_arr[lane + 128] : -3.0e38f;
    float mx = fmaxf(fmaxf(v0, v1), v2);
#pragma unroll
    for (int m = 1; m < 64; m <<= 1) mx = fmaxf(mx, __shfl_xor(mx, m, 64));
    float e0 = __expf(v0 - mx), e1 = __expf(v1 - mx);
    float e2 = (lane < 32) ? __expf(v2 - mx) : 0.f;
    s_arr[lane] = e0; s_arr[lane + 64] = e1;
    if (lane < 32) s_arr[lane + 128] = e2;
    float sm = e0 + e1 + e2;
#pragma unroll
    for (int m = 1; m < 64; m <<= 1) sm += __shfl_xor(sm, m, 64);
    if (lane == 0) red0 = 1.0f / sm;
  }
  __syncthreads();
  const float inv = red0;
  float* ob = HCD + (size_t)b * 48000;
#pragma unroll
  for (int cc = 0; cc < 19; ++cc) {
    int idx = cc * 2560 + tid * 4;
    if (idx < 48000) {
      int row = idx / 300;
      int col = idx - row * 300;
      s16x4 p = *(const s16x4*)&Xbf[laddr(row, col)];
      float sc = s_arr[row] * inv;
      f32x4 o;
#pragma unroll
      for (int j = 0; j < 4; ++j) o[j] = sc * bf2f((unsigned short)p[j]);
      *(f32x4*)(ob + idx) = o;
    }
  }
}

extern "C" void kernel_launch(void* const* d_in, const int* in_sizes, int n_in,
                              void* d_out, int out_size, void* d_ws, size_t ws_size,
                              hipStream_t stream) {
  (void)in_sizes; (void)n_in; (void)out_size; (void)ws_size;
  const float* T      = (const float*)d_in[0];
  const float* CD     = (const float*)d_in[1];
  const float* Wproj  = (const float*)d_in[2];
  const float* bproj  = (const float*)d_in[3];
  const float* WqT_w  = (const float*)d_in[4];
  const float* WqT_b  = (const float*)d_in[5];
  const float* WqCD_w = (const float*)d_in[6];
  const float* WqCD_b = (const float*)d_in[7];
  const float* WkT_w  = (const float*)d_in[8];
  const float* WkT_b  = (const float*)d_in[9];
  const float* WkCD_w = (const float*)d_in[10];
  const float* WkCD_b = (const float*)d_in[11];
  const float* W3_w   = (const float*)d_in[12];
  // W3_b unused: softmax is shift-invariant.

  char* ws = (char*)d_ws;
  size_t off = 0;
  auto alloc = [&](size_t bytes) { void* p = ws + off; off = (off + bytes + 255) & ~(size_t)255; return p; };
  unsigned short* Wb    = (unsigned short*)alloc((size_t)DP * DP * 2);
  unsigned short* MaugT = (unsigned short*)alloc((size_t)DP * DP * 2);
  float* Pmat = (float*)alloc((size_t)DP * DP * 4);

  float* projT = (float*)d_out;
  float* HCD   = (float*)d_out + (size_t)49152000;

  const float isd = 1.0f / sqrtf(300.0f);

  prep1_k<<<dim3(960), dim3(320), 0, stream>>>(Wproj, WqCD_w, WqCD_b, WkCD_w, WkCD_b,
                                               WqT_w, WqT_b, WkT_w, WkT_b,
                                               Wb, MaugT, Pmat, isd);
  fused_k<<<dim3(1024), dim3(640), 0, stream>>>(T, CD, bproj, Wb, MaugT, Pmat, W3_w,
                                                projT, HCD);
}